// Round 1
// baseline (1018.645 us; speedup 1.0000x reference)
//
#include <hip/hip_runtime.h>

// Problem constants
#define TP 512   // passage length
#define TB 8     // batch
#define TD 256   // input size
#define TH 75    // attn hidden
#define THP 80   // padded attn hidden (float4-friendly, pads zeroed)
#define TO 128   // GRU hidden

__device__ __forceinline__ float fast_tanh(float x) {
    // tanh(x) = 1 - 2/(exp(2x)+1); saturates correctly at +/-inf
    return 1.0f - 2.0f / (1.0f + __expf(2.0f * x));
}
__device__ __forceinline__ float fast_sigmoid(float x) {
    return 1.0f / (1.0f + __expf(-x));
}
__device__ __forceinline__ float f4c(const float4 a, int u) {
    return (u == 0) ? a.x : (u == 1) ? a.y : (u == 2) ? a.z : a.w;
}

// ---------------- prep: transpose weights for coalesced GEMM reads ----------
__global__ __launch_bounds__(256) void prep_kernel(
    const float* __restrict__ Wvp1, const float* __restrict__ Wvp2,
    const float* __restrict__ Wg,   const float* __restrict__ wihf,
    const float* __restrict__ wihb, const float* __restrict__ bihf,
    const float* __restrict__ bihb,
    float* __restrict__ WTvp, float* __restrict__ WgT,
    float* __restrict__ WihT, float* __restrict__ bihC)
{
    int idx = blockIdx.x * 256 + threadIdx.x;
    if (idx < 256 * 160) {                      // WTvp[k][o], o<150 = [Wvp1;Wvp2]
        int k = idx / 160, o = idx - k * 160;
        float vv = 0.0f;
        if (o < 75)       vv = Wvp1[o * 256 + k];
        else if (o < 150) vv = Wvp2[(o - 75) * 256 + k];
        WTvp[idx] = vv;
        return;
    }
    idx -= 256 * 160;
    if (idx < 512 * 512) {                      // WgT[k][o] = Wg[o][k]
        int k = idx >> 9, o = idx & 511;
        WgT[idx] = Wg[o * 512 + k];
        return;
    }
    idx -= 512 * 512;
    if (idx < 512 * 768) {                      // WihT[k][o], o<384 fwd else bwd
        int k = idx / 768, o = idx - k * 768;
        WihT[idx] = (o < 384) ? wihf[o * 512 + k] : wihb[(o - 384) * 512 + k];
        return;
    }
    idx -= 512 * 768;
    if (idx < 768) bihC[idx] = (idx < 384) ? bihf[idx] : bihb[idx - 384];
}

// ---------------- Wv1/Wv2 = v @ Wvp{1,2}.T, stored [b][p][80] (pads zero) ----
__global__ __launch_bounds__(256) void wv12_kernel(
    const float* __restrict__ v, const float* __restrict__ WTvp,
    float* __restrict__ Wv1, float* __restrict__ Wv2)
{
    int tid = threadIdx.x;
    int p = blockIdx.x >> 3, b = blockIdx.x & 7;
    __shared__ float vrow[256];
    vrow[tid] = v[blockIdx.x * 256 + tid];   // blockIdx = p*8+b, matches v[p][b][:]
    __syncthreads();
    int ob = (b * TP + p) * THP;
    if (tid < 150) {
        float a0 = 0.f, a1 = 0.f, a2 = 0.f, a3 = 0.f;
        for (int k = 0; k < 256; k += 4) {
            a0 += vrow[k]     * WTvp[(k)     * 160 + tid];
            a1 += vrow[k + 1] * WTvp[(k + 1) * 160 + tid];
            a2 += vrow[k + 2] * WTvp[(k + 2) * 160 + tid];
            a3 += vrow[k + 3] * WTvp[(k + 3) * 160 + tid];
        }
        float acc = (a0 + a1) + (a2 + a3);
        if (tid < 75) Wv1[ob + tid] = acc;
        else          Wv2[ob + tid - 75] = acc;
    } else if (tid < 155) {
        Wv1[ob + 75 + (tid - 150)] = 0.0f;   // zero pads
    } else if (tid < 160) {
        Wv2[ob + 75 + (tid - 155)] = 0.0f;
    }
}

// -------- fused scores -> softmax(i) -> context -> build g=[v,c] ------------
// grid: b in [0,8) x 128 j-tiles of 4; block 256
__global__ __launch_bounds__(256) void attn_kernel(
    const float* __restrict__ v,
    const float* __restrict__ Wv1, const float* __restrict__ Wv2,
    const float* __restrict__ vw, float* __restrict__ g)
{
    int tid = threadIdx.x;
    int b  = blockIdx.x >> 7;
    int j0 = (blockIdx.x & 127) * 4;
    __shared__ float wv1j[4 * THP];
    __shared__ float vws[THP];
    __shared__ float sc[4 * TP];

    if (tid < THP) vws[tid] = (tid < TH) ? vw[tid] : 0.0f;
    for (int e = tid; e < 4 * THP; e += 256) {
        int jj = e / THP, k = e - jj * THP;
        wv1j[e] = Wv1[(b * TP + j0 + jj) * THP + k];
    }
    __syncthreads();

    // ---- scores: sc[jj][i] = sum_h tanh(Wv2[i]+Wv1[j]) * vw[h]
    float4 r2[20];
    for (int rep = 0; rep < 2; ++rep) {
        int i = tid + rep * 256;
        const float4* row = (const float4*)(Wv2 + (b * TP + i) * THP);
#pragma unroll
        for (int kk = 0; kk < 20; ++kk) r2[kk] = row[kk];
#pragma unroll
        for (int jj = 0; jj < 4; ++jj) {
            const float4* w1  = (const float4*)(wv1j + jj * THP);
            const float4* vv4 = (const float4*)vws;
            float acc = 0.0f;
#pragma unroll
            for (int kk = 0; kk < 20; ++kk) {
                float4 a = r2[kk], bb = w1[kk], c = vv4[kk];
                acc += fast_tanh(a.x + bb.x) * c.x;
                acc += fast_tanh(a.y + bb.y) * c.y;
                acc += fast_tanh(a.z + bb.z) * c.z;
                acc += fast_tanh(a.w + bb.w) * c.w;
            }
            sc[jj * TP + i] = acc;
        }
    }
    __syncthreads();

    // ---- softmax over i (axis 0), one wave per jj
    {
        int jj = tid >> 6, l = tid & 63;
        float m = -1e30f;
#pragma unroll
        for (int q = 0; q < 8; ++q) m = fmaxf(m, sc[jj * TP + l + q * 64]);
#pragma unroll
        for (int s = 32; s > 0; s >>= 1) m = fmaxf(m, __shfl_xor(m, s));
        float e[8];
        float sum = 0.0f;
#pragma unroll
        for (int q = 0; q < 8; ++q) { e[q] = __expf(sc[jj * TP + l + q * 64] - m); sum += e[q]; }
#pragma unroll
        for (int s = 32; s > 0; s >>= 1) sum += __shfl_xor(sum, s);
        float inv = 1.0f / sum;
#pragma unroll
        for (int q = 0; q < 8; ++q) sc[jj * TP + l + q * 64] = e[q] * inv;
    }
    __syncthreads();

    // ---- context: c[j,b,d] = sum_i a[i]*v[i,b,d]; thread owns d = tid
    float acc[4] = {0.f, 0.f, 0.f, 0.f};
    const float* vb = v + b * TD + tid;
    for (int i4 = 0; i4 < TP / 4; ++i4) {
        float4 a0 = ((const float4*)(sc + 0 * TP))[i4];
        float4 a1 = ((const float4*)(sc + 1 * TP))[i4];
        float4 a2 = ((const float4*)(sc + 2 * TP))[i4];
        float4 a3 = ((const float4*)(sc + 3 * TP))[i4];
#pragma unroll
        for (int u = 0; u < 4; ++u) {
            float va = vb[(i4 * 4 + u) * (TB * TD)];
            acc[0] += f4c(a0, u) * va;
            acc[1] += f4c(a1, u) * va;
            acc[2] += f4c(a2, u) * va;
            acc[3] += f4c(a3, u) * va;
        }
    }
#pragma unroll
    for (int jj = 0; jj < 4; ++jj) {
        int base = ((j0 + jj) * TB + b) * 512;
        g[base + tid]       = v[((j0 + jj) * TB + b) * TD + tid];
        g[base + 256 + tid] = acc[jj];
    }
}

// -------- fused gate (sigmoid(g Wg^T)*g) + GRU input projections ------------
// grid 256 blocks x 512 threads; each block owns 16 rows of g (rows = p*8+b)
__global__ __launch_bounds__(512) void gatexp_kernel(
    const float* __restrict__ g, const float* __restrict__ WgT,
    const float* __restrict__ WihT, const float* __restrict__ bihC,
    float* __restrict__ xpf, float* __restrict__ xpb)
{
    __shared__ float gt[16 * 512];
    int tid = threadIdx.x;
    int r0 = blockIdx.x * 16;
    const float4* gsrc = (const float4*)(g + r0 * 512);
    for (int e = tid; e < 2048; e += 512) ((float4*)gt)[e] = gsrc[e];
    __syncthreads();

    int tx = tid & 63, ty = tid >> 6;    // ty in [0,8): rows 2ty, 2ty+1
    int row0 = ty * 2, row1 = ty * 2 + 1;

    // ---- phase 1: gate matmul, N=512
    float acc[2][8];
#pragma unroll
    for (int r = 0; r < 2; ++r)
#pragma unroll
        for (int u = 0; u < 8; ++u) acc[r][u] = 0.f;

    for (int k4 = 0; k4 < 128; ++k4) {
        float4 g0 = ((const float4*)(gt + row0 * 512))[k4];
        float4 g1 = ((const float4*)(gt + row1 * 512))[k4];
#pragma unroll
        for (int u = 0; u < 4; ++u) {
            int k = k4 * 4 + u;
            float4 wA = ((const float4*)(WgT + k * 512))[tx];
            float4 wB = ((const float4*)(WgT + k * 512 + 256))[tx];
            float ga = f4c(g0, u), gb = f4c(g1, u);
            acc[0][0] += ga * wA.x; acc[0][1] += ga * wA.y; acc[0][2] += ga * wA.z; acc[0][3] += ga * wA.w;
            acc[0][4] += ga * wB.x; acc[0][5] += ga * wB.y; acc[0][6] += ga * wB.z; acc[0][7] += ga * wB.w;
            acc[1][0] += gb * wA.x; acc[1][1] += gb * wA.y; acc[1][2] += gb * wA.z; acc[1][3] += gb * wA.w;
            acc[1][4] += gb * wB.x; acc[1][5] += gb * wB.y; acc[1][6] += gb * wB.z; acc[1][7] += gb * wB.w;
        }
    }
    // gated = sigmoid(acc) * g   (keep in regs, then write back to LDS)
    float gated[2][8];
#pragma unroll
    for (int r = 0; r < 2; ++r) {
        int row = ty * 2 + r;
#pragma unroll
        for (int h = 0; h < 2; ++h) {
            int o0 = h * 256 + tx * 4;
#pragma unroll
            for (int u = 0; u < 4; ++u)
                gated[r][h * 4 + u] = fast_sigmoid(acc[r][h * 4 + u]) * gt[row * 512 + o0 + u];
        }
    }
    __syncthreads();
#pragma unroll
    for (int r = 0; r < 2; ++r) {
        int row = ty * 2 + r;
#pragma unroll
        for (int h = 0; h < 2; ++h) {
            int o0 = h * 256 + tx * 4;
#pragma unroll
            for (int u = 0; u < 4; ++u) gt[row * 512 + o0 + u] = gated[r][h * 4 + u];
        }
    }
    __syncthreads();

    // ---- phase 2: xp = gated @ [w_ih_f; w_ih_b]^T + bias, N=768
    float a2[2][12];
#pragma unroll
    for (int r = 0; r < 2; ++r)
#pragma unroll
        for (int u = 0; u < 12; ++u) a2[r][u] = 0.f;

    for (int k4 = 0; k4 < 128; ++k4) {
        float4 g0 = ((const float4*)(gt + row0 * 512))[k4];
        float4 g1 = ((const float4*)(gt + row1 * 512))[k4];
#pragma unroll
        for (int u = 0; u < 4; ++u) {
            int k = k4 * 4 + u;
            const float4* wr = (const float4*)(WihT + k * 768);
            float4 w0 = wr[tx];
            float4 w1 = wr[64 + tx];
            float4 w2 = wr[128 + tx];
            float ga = f4c(g0, u), gb = f4c(g1, u);
            a2[0][0] += ga * w0.x; a2[0][1]  += ga * w0.y; a2[0][2]  += ga * w0.z; a2[0][3]  += ga * w0.w;
            a2[0][4] += ga * w1.x; a2[0][5]  += ga * w1.y; a2[0][6]  += ga * w1.z; a2[0][7]  += ga * w1.w;
            a2[0][8] += ga * w2.x; a2[0][9]  += ga * w2.y; a2[0][10] += ga * w2.z; a2[0][11] += ga * w2.w;
            a2[1][0] += gb * w0.x; a2[1][1]  += gb * w0.y; a2[1][2]  += gb * w0.z; a2[1][3]  += gb * w0.w;
            a2[1][4] += gb * w1.x; a2[1][5]  += gb * w1.y; a2[1][6]  += gb * w1.z; a2[1][7]  += gb * w1.w;
            a2[1][8] += gb * w2.x; a2[1][9]  += gb * w2.y; a2[1][10] += gb * w2.z; a2[1][11] += gb * w2.w;
        }
    }
#pragma unroll
    for (int r = 0; r < 2; ++r) {
        int row = r0 + ty * 2 + r;
#pragma unroll
        for (int h = 0; h < 3; ++h) {
            int o0 = h * 256 + tx * 4;
            float4 bv = *(const float4*)(bihC + o0);
            float4 val;
            val.x = a2[r][h * 4 + 0] + bv.x;
            val.y = a2[r][h * 4 + 1] + bv.y;
            val.z = a2[r][h * 4 + 2] + bv.z;
            val.w = a2[r][h * 4 + 3] + bv.w;
            if (o0 < 384) *(float4*)(xpf + row * 384 + o0)       = val;
            else          *(float4*)(xpb + row * 384 + o0 - 384) = val;
        }
    }
}

// ---------------- GRU recurrence, one block per (dir, batch) ----------------
// 768 threads: thread t owns row o=t>>1 of w_hh, half=t&1 of the K=128 dot
__global__ __launch_bounds__(768) void gru_kernel(
    const float* __restrict__ xpf, const float* __restrict__ xpb,
    const float* __restrict__ whhf, const float* __restrict__ whhb,
    const float* __restrict__ bhhf, const float* __restrict__ bhhb,
    float* __restrict__ out)
{
    int tid = threadIdx.x;
    int dir = blockIdx.x >> 3;
    int b   = blockIdx.x & 7;
    const float* xp  = dir ? xpb  : xpf;
    const float* whh = dir ? whhb : whhf;
    const float* bhh = dir ? bhhb : bhhf;

    __shared__ float hbuf[TO];
    __shared__ float ghbuf[3 * TO];

    int o = tid >> 1, half = tid & 1;
    float4 w[16];
    const float4* wrow = (const float4*)(whh + o * TO + half * 64);
#pragma unroll
    for (int kk = 0; kk < 16; ++kk) w[kk] = wrow[kk];

    float br = 0.f, bz = 0.f, bn = 0.f, h = 0.f;
    if (tid < TO) {
        br = bhh[tid]; bz = bhh[TO + tid]; bn = bhh[2 * TO + tid];
        hbuf[tid] = 0.0f;
    }
    __syncthreads();

    for (int s = 0; s < TP; ++s) {
        int t = dir ? (TP - 1 - s) : s;
        float xr = 0.f, xz = 0.f, xn = 0.f;
        if (tid < TO) {   // issue early; latency overlaps the matvec below
            const float* xpt = xp + (t * TB + b) * 384;
            xr = xpt[tid]; xz = xpt[TO + tid]; xn = xpt[2 * TO + tid];
        }
        // gh[o] partial over this thread's half of K
        float acc0 = 0.f, acc1 = 0.f;
        const float4* h4 = ((const float4*)hbuf) + half * 16;
#pragma unroll
        for (int kk = 0; kk < 16; kk += 2) {
            float4 hv0 = h4[kk], hv1 = h4[kk + 1];
            acc0 += w[kk].x * hv0.x + w[kk].y * hv0.y + w[kk].z * hv0.z + w[kk].w * hv0.w;
            acc1 += w[kk+1].x * hv1.x + w[kk+1].y * hv1.y + w[kk+1].z * hv1.z + w[kk+1].w * hv1.w;
        }
        float acc = acc0 + acc1;
        acc += __shfl_xor(acc, 1);
        if (half == 0) ghbuf[o] = acc;
        __syncthreads();
        if (tid < TO) {
            float r = fast_sigmoid(xr + ghbuf[tid] + br);
            float z = fast_sigmoid(xz + ghbuf[TO + tid] + bz);
            float n = fast_tanh(xn + r * (ghbuf[2 * TO + tid] + bn));
            h = (1.0f - z) * n + z * h;
            hbuf[tid] = h;
            out[(t * TB + b) * 256 + dir * TO + tid] = h;
        }
        __syncthreads();
    }
}

extern "C" void kernel_launch(void* const* d_in, const int* in_sizes, int n_in,
                              void* d_out, int out_size, void* d_ws, size_t ws_size,
                              hipStream_t stream) {
    const float* v    = (const float*)d_in[0];
    const float* Wvp1 = (const float*)d_in[1];
    const float* Wvp2 = (const float*)d_in[2];
    const float* vw   = (const float*)d_in[3];
    const float* Wg   = (const float*)d_in[4];
    const float* wihf = (const float*)d_in[5];
    const float* whhf = (const float*)d_in[6];
    const float* bihf = (const float*)d_in[7];
    const float* bhhf = (const float*)d_in[8];
    const float* wihb = (const float*)d_in[9];
    const float* whhb = (const float*)d_in[10];
    const float* bihb = (const float*)d_in[11];
    const float* bhhb = (const float*)d_in[12];

    float* ws   = (float*)d_ws;
    float* WTvp = ws;                    // 256*160      = 40960
    float* WgT  = WTvp + 40960;          // 512*512      = 262144
    float* WihT = WgT + 262144;          // 512*768      = 393216
    float* bihC = WihT + 393216;         // 768
    float* Wv1  = bihC + 768;            // 8*512*80     = 327680
    float* Wv2  = Wv1 + 327680;          // 327680
    float* g    = Wv2 + 327680;          // 4096*512     = 2097152
    float* xpf  = g + 2097152;           // 4096*384     = 1572864
    float* xpb  = xpf + 1572864;         // 1572864
    float* out  = (float*)d_out;

    prep_kernel<<<2724, 256, 0, stream>>>(Wvp1, Wvp2, Wg, wihf, wihb, bihf, bihb,
                                          WTvp, WgT, WihT, bihC);
    wv12_kernel<<<4096, 256, 0, stream>>>(v, WTvp, Wv1, Wv2);
    attn_kernel<<<1024, 256, 0, stream>>>(v, Wv1, Wv2, vw, g);
    gatexp_kernel<<<256, 512, 0, stream>>>(g, WgT, WihT, bihC, xpf, xpb);
    gru_kernel<<<16, 768, 0, stream>>>(xpf, xpb, whhf, whhb, bhhf, bhhb, out);
}

// Round 2
// 734.518 us; speedup vs baseline: 1.3868x; 1.3868x over previous
//
#include <hip/hip_runtime.h>

// Problem constants
#define TP 512   // passage length
#define TB 8     // batch
#define TD 256   // input size
#define TH 75    // attn hidden
#define THP 80   // padded attn hidden (float4-friendly, pads zeroed)
#define TO 128   // GRU hidden

__device__ __forceinline__ float fast_rcp(float x) { return __builtin_amdgcn_rcpf(x); }
__device__ __forceinline__ float fast_tanh(float x) {
    // tanh(x) = 1 - 2/(exp(2x)+1); saturates correctly at +/-inf
    return 1.0f - 2.0f * fast_rcp(1.0f + __expf(2.0f * x));
}
__device__ __forceinline__ float fast_sigmoid(float x) {
    return fast_rcp(1.0f + __expf(-x));
}
__device__ __forceinline__ float f4c(const float4 a, int u) {
    return (u == 0) ? a.x : (u == 1) ? a.y : (u == 2) ? a.z : a.w;
}
__device__ __forceinline__ float dot4(const float4 a, const float4 b) {
    return a.x * b.x + a.y * b.y + a.z * b.z + a.w * b.w;
}

// ---------------- prep: transpose weights for coalesced GEMM reads ----------
__global__ __launch_bounds__(256) void prep_kernel(
    const float* __restrict__ Wvp1, const float* __restrict__ Wvp2,
    const float* __restrict__ Wg,   const float* __restrict__ wihf,
    const float* __restrict__ wihb, const float* __restrict__ bihf,
    const float* __restrict__ bihb,
    float* __restrict__ WTvp, float* __restrict__ WgT,
    float* __restrict__ WihT, float* __restrict__ bihC)
{
    int idx = blockIdx.x * 256 + threadIdx.x;
    if (idx < 256 * 160) {                      // WTvp[k][o], o<150 = [Wvp1;Wvp2]
        int k = idx / 160, o = idx - k * 160;
        float vv = 0.0f;
        if (o < 75)       vv = Wvp1[o * 256 + k];
        else if (o < 150) vv = Wvp2[(o - 75) * 256 + k];
        WTvp[idx] = vv;
        return;
    }
    idx -= 256 * 160;
    if (idx < 512 * 512) {                      // WgT[k][o] = Wg[o][k]
        int k = idx >> 9, o = idx & 511;
        WgT[idx] = Wg[o * 512 + k];
        return;
    }
    idx -= 512 * 512;
    if (idx < 512 * 768) {                      // WihT[k][o], o<384 fwd else bwd
        int k = idx / 768, o = idx - k * 768;
        WihT[idx] = (o < 384) ? wihf[o * 512 + k] : wihb[(o - 384) * 512 + k];
        return;
    }
    idx -= 512 * 768;
    if (idx < 768) bihC[idx] = (idx < 384) ? bihf[idx] : bihb[idx - 384];
}

// ---------------- Wv1/Wv2 = v @ Wvp{1,2}.T, stored [b][p][80] (pads zero) ----
__global__ __launch_bounds__(256) void wv12_kernel(
    const float* __restrict__ v, const float* __restrict__ WTvp,
    float* __restrict__ Wv1, float* __restrict__ Wv2)
{
    int tid = threadIdx.x;
    int p = blockIdx.x >> 3, b = blockIdx.x & 7;
    __shared__ float vrow[256];
    vrow[tid] = v[blockIdx.x * 256 + tid];   // blockIdx = p*8+b, matches v[p][b][:]
    __syncthreads();
    int ob = (b * TP + p) * THP;
    if (tid < 150) {
        float a0 = 0.f, a1 = 0.f, a2 = 0.f, a3 = 0.f;
        for (int k = 0; k < 256; k += 4) {
            a0 += vrow[k]     * WTvp[(k)     * 160 + tid];
            a1 += vrow[k + 1] * WTvp[(k + 1) * 160 + tid];
            a2 += vrow[k + 2] * WTvp[(k + 2) * 160 + tid];
            a3 += vrow[k + 3] * WTvp[(k + 3) * 160 + tid];
        }
        float acc = (a0 + a1) + (a2 + a3);
        if (tid < 75) Wv1[ob + tid] = acc;
        else          Wv2[ob + tid - 75] = acc;
    } else if (tid < 155) {
        Wv1[ob + 75 + (tid - 150)] = 0.0f;   // zero pads
    } else if (tid < 160) {
        Wv2[ob + 75 + (tid - 155)] = 0.0f;
    }
}

// -------- fused scores -> softmax(i) -> context -> build g=[v,c] ------------
// grid: b in [0,8) x 128 j-tiles of 4; block 256
__global__ __launch_bounds__(256) void attn_kernel(
    const float* __restrict__ v,
    const float* __restrict__ Wv1, const float* __restrict__ Wv2,
    const float* __restrict__ vw, float* __restrict__ g)
{
    int tid = threadIdx.x;
    int b  = blockIdx.x >> 7;
    int j0 = (blockIdx.x & 127) * 4;
    __shared__ float wv1j[4 * THP];
    __shared__ float vws[THP];
    __shared__ float sc[4 * TP];

    if (tid < THP) vws[tid] = (tid < TH) ? vw[tid] : 0.0f;
    for (int e = tid; e < 4 * THP; e += 256) {
        int jj = e / THP, k = e - jj * THP;
        wv1j[e] = Wv1[(b * TP + j0 + jj) * THP + k];
    }
    __syncthreads();

    // ---- scores: sc[jj][i] = sum_h tanh(Wv2[i]+Wv1[j]) * vw[h]
    float4 r2[20];
    for (int rep = 0; rep < 2; ++rep) {
        int i = tid + rep * 256;
        const float4* row = (const float4*)(Wv2 + (b * TP + i) * THP);
#pragma unroll
        for (int kk = 0; kk < 20; ++kk) r2[kk] = row[kk];
#pragma unroll
        for (int jj = 0; jj < 4; ++jj) {
            const float4* w1  = (const float4*)(wv1j + jj * THP);
            const float4* vv4 = (const float4*)vws;
            float acc = 0.0f;
#pragma unroll
            for (int kk = 0; kk < 20; ++kk) {
                float4 a = r2[kk], bb = w1[kk], c = vv4[kk];
                acc += fast_tanh(a.x + bb.x) * c.x;
                acc += fast_tanh(a.y + bb.y) * c.y;
                acc += fast_tanh(a.z + bb.z) * c.z;
                acc += fast_tanh(a.w + bb.w) * c.w;
            }
            sc[jj * TP + i] = acc;
        }
    }
    __syncthreads();

    // ---- softmax over i (axis 0), one wave per jj
    {
        int jj = tid >> 6, l = tid & 63;
        float m = -1e30f;
#pragma unroll
        for (int q = 0; q < 8; ++q) m = fmaxf(m, sc[jj * TP + l + q * 64]);
#pragma unroll
        for (int s = 32; s > 0; s >>= 1) m = fmaxf(m, __shfl_xor(m, s));
        float e[8];
        float sum = 0.0f;
#pragma unroll
        for (int q = 0; q < 8; ++q) { e[q] = __expf(sc[jj * TP + l + q * 64] - m); sum += e[q]; }
#pragma unroll
        for (int s = 32; s > 0; s >>= 1) sum += __shfl_xor(sum, s);
        float inv = fast_rcp(sum);
#pragma unroll
        for (int q = 0; q < 8; ++q) sc[jj * TP + l + q * 64] = e[q] * inv;
    }
    __syncthreads();

    // ---- context: c[j,b,d] = sum_i a[i]*v[i,b,d]; thread owns d = tid
    float acc[4] = {0.f, 0.f, 0.f, 0.f};
    const float* vb = v + b * TD + tid;
    for (int i4 = 0; i4 < TP / 4; ++i4) {
        float4 a0 = ((const float4*)(sc + 0 * TP))[i4];
        float4 a1 = ((const float4*)(sc + 1 * TP))[i4];
        float4 a2 = ((const float4*)(sc + 2 * TP))[i4];
        float4 a3 = ((const float4*)(sc + 3 * TP))[i4];
#pragma unroll
        for (int u = 0; u < 4; ++u) {
            float va = vb[(i4 * 4 + u) * (TB * TD)];
            acc[0] += f4c(a0, u) * va;
            acc[1] += f4c(a1, u) * va;
            acc[2] += f4c(a2, u) * va;
            acc[3] += f4c(a3, u) * va;
        }
    }
#pragma unroll
    for (int jj = 0; jj < 4; ++jj) {
        int base = ((j0 + jj) * TB + b) * 512;
        g[base + tid]       = v[((j0 + jj) * TB + b) * TD + tid];
        g[base + 256 + tid] = acc[jj];
    }
}

// -------- fused gate (sigmoid(g Wg^T)*g) + GRU input projections ------------
// 512 threads = 8 waves = (2 row-groups of 8 rows) x (4 col-groups).
// Waves read DISJOINT weight columns (redundancy 2, not 8); g broadcasts come
// from a transposed padded LDS copy (4 rows per ds_read_b128, pure broadcast).
__global__ __launch_bounds__(512) void gatexp_kernel(
    const float* __restrict__ g, const float* __restrict__ WgT,
    const float* __restrict__ WihT, const float* __restrict__ bihC,
    float* __restrict__ xpf, float* __restrict__ xpb)
{
    __shared__ float gt[16 * 512];      // row-major original g
    __shared__ float gT[512 * 20];      // transposed, padded stride 20: gT[k*20+r]
    int tid = threadIdx.x;
    int r0 = blockIdx.x * 16;

    // ---- stage both copies
    const float4* gsrc = (const float4*)(g + r0 * 512);
    for (int e = tid; e < 2048; e += 512) {
        float4 vv = gsrc[e];
        ((float4*)gt)[e] = vv;
        int r = e >> 7, k4 = e & 127;
        gT[(k4 * 4 + 0) * 20 + r] = vv.x;
        gT[(k4 * 4 + 1) * 20 + r] = vv.y;
        gT[(k4 * 4 + 2) * 20 + r] = vv.z;
        gT[(k4 * 4 + 3) * 20 + r] = vv.w;
    }
    __syncthreads();

    int tx = tid & 63, w = tid >> 6;
    int rg = w >> 2;                 // rows rg*8 .. rg*8+7
    int cg = w & 3;

    // ---- phase 1: gate matmul (N=512); cols = cg*128 + tx*2 + {0,1}
    float acc[8][2];
#pragma unroll
    for (int r = 0; r < 8; ++r) { acc[r][0] = 0.f; acc[r][1] = 0.f; }
    int col = cg * 128 + tx * 2;
    {
        const float* wp = WgT + col;
        const float* gp = gT + rg * 8;
#pragma unroll 4
        for (int k = 0; k < 512; ++k) {
            float2 wv = *(const float2*)wp;
            float4 ga = *(const float4*)gp;
            float4 gb = *(const float4*)(gp + 4);
            acc[0][0] += ga.x * wv.x; acc[0][1] += ga.x * wv.y;
            acc[1][0] += ga.y * wv.x; acc[1][1] += ga.y * wv.y;
            acc[2][0] += ga.z * wv.x; acc[2][1] += ga.z * wv.y;
            acc[3][0] += ga.w * wv.x; acc[3][1] += ga.w * wv.y;
            acc[4][0] += gb.x * wv.x; acc[4][1] += gb.x * wv.y;
            acc[5][0] += gb.y * wv.x; acc[5][1] += gb.y * wv.y;
            acc[6][0] += gb.z * wv.x; acc[6][1] += gb.z * wv.y;
            acc[7][0] += gb.w * wv.x; acc[7][1] += gb.w * wv.y;
            wp += 512; gp += 20;
        }
    }
    // gated = sigmoid(acc) * g_orig  (g_orig from row-major copy)
    float gated[8][2];
#pragma unroll
    for (int r = 0; r < 8; ++r) {
        float2 go = *(const float2*)(gt + (rg * 8 + r) * 512 + col);
        gated[r][0] = fast_sigmoid(acc[r][0]) * go.x;
        gated[r][1] = fast_sigmoid(acc[r][1]) * go.y;
    }
    __syncthreads();   // all phase-1 gT reads done before overwrite
#pragma unroll
    for (int c = 0; c < 2; ++c) {
        float4 p0 = { gated[0][c], gated[1][c], gated[2][c], gated[3][c] };
        float4 p1 = { gated[4][c], gated[5][c], gated[6][c], gated[7][c] };
        *(float4*)(gT + (col + c) * 20 + rg * 8)     = p0;
        *(float4*)(gT + (col + c) * 20 + rg * 8 + 4) = p1;
    }
    __syncthreads();

    // ---- phase 2: xp = gated @ Wih^T (N=768); cols2 = cg*192 + tx + {0,64,128}
    float a2[8][3];
#pragma unroll
    for (int r = 0; r < 8; ++r) { a2[r][0] = 0.f; a2[r][1] = 0.f; a2[r][2] = 0.f; }
    int col2 = cg * 192 + tx;
    {
        const float* wp = WihT + col2;
        const float* gp = gT + rg * 8;
#pragma unroll 4
        for (int k = 0; k < 512; ++k) {
            float w0 = wp[0], w1 = wp[64], w2 = wp[128];
            float4 ga = *(const float4*)gp;
            float4 gb = *(const float4*)(gp + 4);
            a2[0][0] += ga.x * w0; a2[0][1] += ga.x * w1; a2[0][2] += ga.x * w2;
            a2[1][0] += ga.y * w0; a2[1][1] += ga.y * w1; a2[1][2] += ga.y * w2;
            a2[2][0] += ga.z * w0; a2[2][1] += ga.z * w1; a2[2][2] += ga.z * w2;
            a2[3][0] += ga.w * w0; a2[3][1] += ga.w * w1; a2[3][2] += ga.w * w2;
            a2[4][0] += gb.x * w0; a2[4][1] += gb.x * w1; a2[4][2] += gb.x * w2;
            a2[5][0] += gb.y * w0; a2[5][1] += gb.y * w1; a2[5][2] += gb.y * w2;
            a2[6][0] += gb.z * w0; a2[6][1] += gb.z * w1; a2[6][2] += gb.z * w2;
            a2[7][0] += gb.w * w0; a2[7][1] += gb.w * w1; a2[7][2] += gb.w * w2;
            wp += 768; gp += 20;
        }
    }
#pragma unroll
    for (int c = 0; c < 3; ++c) {
        int oc = col2 + c * 64;
        float bv = bihC[oc];
        float* dst;
        if (oc < 384) dst = xpf + oc;
        else          dst = xpb + oc - 384;
#pragma unroll
        for (int r = 0; r < 8; ++r) {
            int row = r0 + rg * 8 + r;
            dst[row * 384] = a2[r][c] + bv;
        }
    }
}

// ---------------- GRU recurrence, one block per (dir, batch) ----------------
// 512 threads: thread owns (o = tid>>2, K-quarter q = tid&3). w_hh rows for all
// 3 gates live in 96 VGPRs. h in ping-pong LDS, quarter-padded (stride 36) to
// kill 4-way bank aliasing. ONE barrier per step; xp prefetched a step ahead.
__global__ __launch_bounds__(512) void gru_kernel(
    const float* __restrict__ xpf, const float* __restrict__ xpb,
    const float* __restrict__ whhf, const float* __restrict__ whhb,
    const float* __restrict__ bhhf, const float* __restrict__ bhhb,
    float* __restrict__ out)
{
    int tid = threadIdx.x;
    int dir = blockIdx.x >> 3;
    int b   = blockIdx.x & 7;
    const float* xp  = dir ? xpb  : xpf;
    const float* whh = dir ? whhb : whhf;
    const float* bhh = dir ? bhhb : bhhf;

    __shared__ float hb[2][148];     // 4 quarters of 32, stride 36 (pad 4)

    int o = tid >> 2, q = tid & 3;

    float4 wr[8], wz[8], wn[8];
    {
        const float4* pr = (const float4*)(whh + (o)        * TO + q * 32);
        const float4* pz = (const float4*)(whh + (TO + o)   * TO + q * 32);
        const float4* pn = (const float4*)(whh + (2*TO + o) * TO + q * 32);
#pragma unroll
        for (int kk = 0; kk < 8; ++kk) { wr[kk] = pr[kk]; wz[kk] = pz[kk]; wn[kk] = pn[kk]; }
    }

    float br = 0.f, bz = 0.f, bn = 0.f, h = 0.f;
    float xr = 0.f, xz = 0.f, xn = 0.f;
    if (q == 0) {
        br = bhh[o]; bz = bhh[TO + o]; bn = bhh[2 * TO + o];
        int t0 = dir ? (TP - 1) : 0;
        const float* xpt = xp + (t0 * TB + b) * 384;
        xr = xpt[o]; xz = xpt[TO + o]; xn = xpt[2 * TO + o];
    }
    if (tid < TO) hb[0][(tid >> 5) * 36 + (tid & 31)] = 0.0f;
    __syncthreads();

    for (int s = 0; s < TP; ++s) {
        int t = dir ? (TP - 1 - s) : s;
        int cur = s & 1;
        const float4* h4 = (const float4*)(hb[cur] + q * 36);
        float ar = 0.f, az = 0.f, an = 0.f;
#pragma unroll
        for (int kk = 0; kk < 8; ++kk) {
            float4 hv = h4[kk];
            ar += dot4(wr[kk], hv);
            az += dot4(wz[kk], hv);
            an += dot4(wn[kk], hv);
        }
        ar += __shfl_xor(ar, 1); ar += __shfl_xor(ar, 2);
        az += __shfl_xor(az, 1); az += __shfl_xor(az, 2);
        an += __shfl_xor(an, 1); an += __shfl_xor(an, 2);
        if (q == 0) {
            float r = fast_sigmoid(xr + ar + br);
            float z = fast_sigmoid(xz + az + bz);
            float n = fast_tanh(xn + r * (an + bn));
            h = (1.0f - z) * n + z * h;
            hb[cur ^ 1][(o >> 5) * 36 + (o & 31)] = h;
            out[(t * TB + b) * 256 + dir * TO + o] = h;
            // prefetch next step's xp
            int sn = (s + 1 < TP) ? s + 1 : s;
            int tn = dir ? (TP - 1 - sn) : sn;
            const float* xpt = xp + (tn * TB + b) * 384;
            xr = xpt[o]; xz = xpt[TO + o]; xn = xpt[2 * TO + o];
        }
        __syncthreads();
    }
}

extern "C" void kernel_launch(void* const* d_in, const int* in_sizes, int n_in,
                              void* d_out, int out_size, void* d_ws, size_t ws_size,
                              hipStream_t stream) {
    const float* v    = (const float*)d_in[0];
    const float* Wvp1 = (const float*)d_in[1];
    const float* Wvp2 = (const float*)d_in[2];
    const float* vw   = (const float*)d_in[3];
    const float* Wg   = (const float*)d_in[4];
    const float* wihf = (const float*)d_in[5];
    const float* whhf = (const float*)d_in[6];
    const float* bihf = (const float*)d_in[7];
    const float* bhhf = (const float*)d_in[8];
    const float* wihb = (const float*)d_in[9];
    const float* whhb = (const float*)d_in[10];
    const float* bihb = (const float*)d_in[11];
    const float* bhhb = (const float*)d_in[12];

    float* ws   = (float*)d_ws;
    float* WTvp = ws;                    // 256*160      = 40960
    float* WgT  = WTvp + 40960;          // 512*512      = 262144
    float* WihT = WgT + 262144;          // 512*768      = 393216
    float* bihC = WihT + 393216;         // 768
    float* Wv1  = bihC + 768;            // 8*512*80     = 327680
    float* Wv2  = Wv1 + 327680;          // 327680
    float* g    = Wv2 + 327680;          // 4096*512     = 2097152
    float* xpf  = g + 2097152;           // 4096*384     = 1572864
    float* xpb  = xpf + 1572864;         // 1572864
    float* out  = (float*)d_out;

    prep_kernel<<<2724, 256, 0, stream>>>(Wvp1, Wvp2, Wg, wihf, wihb, bihf, bihb,
                                          WTvp, WgT, WihT, bihC);
    wv12_kernel<<<4096, 256, 0, stream>>>(v, WTvp, Wv1, Wv2);
    attn_kernel<<<1024, 256, 0, stream>>>(v, Wv1, Wv2, vw, g);
    gatexp_kernel<<<256, 512, 0, stream>>>(g, WgT, WihT, bihC, xpf, xpb);
    gru_kernel<<<16, 512, 0, stream>>>(xpf, xpb, whhf, whhb, bhhf, bhhb, out);
}

// Round 3
// 674.070 us; speedup vs baseline: 1.5112x; 1.0897x over previous
//
#include <hip/hip_runtime.h>

// Problem constants
#define TP 512   // passage length
#define TB 8     // batch
#define TD 256   // input size
#define TH 75    // attn hidden
#define THP 80   // padded attn hidden (float4-friendly, pads zeroed)
#define TO 128   // GRU hidden

typedef _Float16 half_t;
typedef _Float16 half2v __attribute__((ext_vector_type(2)));
typedef _Float16 half8v __attribute__((ext_vector_type(8)));

union H8 { half8v v8; half2v v2[4]; };

__device__ __forceinline__ float fast_rcp(float x) { return __builtin_amdgcn_rcpf(x); }
__device__ __forceinline__ float fast_tanh(float x) {
    return 1.0f - 2.0f * fast_rcp(1.0f + __expf(2.0f * x));
}
__device__ __forceinline__ float fast_sigmoid(float x) {
    return fast_rcp(1.0f + __expf(-x));
}
__device__ __forceinline__ float f4c(const float4 a, int u) {
    return (u == 0) ? a.x : (u == 1) ? a.y : (u == 2) ? a.z : a.w;
}
__device__ __forceinline__ float fdot2h(half2v a, half2v b, float c) {
#if __has_builtin(__builtin_amdgcn_fdot2)
    return __builtin_amdgcn_fdot2(a, b, c, false);
#else
    return c + (float)a[0] * (float)b[0] + (float)a[1] * (float)b[1];
#endif
}
// score partial: sum c * rcp(1+exp(2(a+b)));  tanh(x) = 1 - 2*rcp(1+exp(2x))
__device__ __forceinline__ float rterm4(float4 a, float4 b, float4 c) {
    float s;
    s  = c.x * fast_rcp(1.0f + __expf(2.0f * (a.x + b.x)));
    s += c.y * fast_rcp(1.0f + __expf(2.0f * (a.y + b.y)));
    s += c.z * fast_rcp(1.0f + __expf(2.0f * (a.z + b.z)));
    s += c.w * fast_rcp(1.0f + __expf(2.0f * (a.w + b.w)));
    return s;
}

// ---------------- prep: transpose weights + f16 GRU weights -----------------
__global__ __launch_bounds__(256) void prep_kernel(
    const float* __restrict__ Wvp1, const float* __restrict__ Wvp2,
    const float* __restrict__ Wg,   const float* __restrict__ wihf,
    const float* __restrict__ wihb, const float* __restrict__ bihf,
    const float* __restrict__ bihb, const float* __restrict__ whhf,
    const float* __restrict__ whhb,
    float* __restrict__ WTvp, float* __restrict__ WgT,
    float* __restrict__ WihT, float* __restrict__ bihC,
    half_t* __restrict__ whh16)
{
    int idx = blockIdx.x * 256 + threadIdx.x;
    if (idx < 256 * 160) {                      // WTvp[k][o], o<150 = [Wvp1;Wvp2]
        int k = idx / 160, o = idx - k * 160;
        float vv = 0.0f;
        if (o < 75)       vv = Wvp1[o * 256 + k];
        else if (o < 150) vv = Wvp2[(o - 75) * 256 + k];
        WTvp[idx] = vv;
        return;
    }
    idx -= 256 * 160;
    if (idx < 512 * 512) {                      // WgT[k][o] = Wg[o][k]
        int k = idx >> 9, o = idx & 511;
        WgT[idx] = Wg[o * 512 + k];
        return;
    }
    idx -= 512 * 512;
    if (idx < 512 * 768) {                      // WihT[k][o], o<384 fwd else bwd
        int k = idx / 768, o = idx - k * 768;
        WihT[idx] = (o < 384) ? wihf[o * 512 + k] : wihb[(o - 384) * 512 + k];
        return;
    }
    idx -= 512 * 768;
    if (idx < 768) { bihC[idx] = (idx < 384) ? bihf[idx] : bihb[idx - 384]; return; }
    idx -= 768;
    if (idx < 2 * 3 * TO * TO) {                // whh16[dir][(g*128+o)*128+k]
        int d = idx / (3 * TO * TO), i = idx - d * (3 * TO * TO);
        whh16[idx] = (half_t)(d ? whhb[i] : whhf[i]);
    }
}

// ---------------- Wv1/Wv2 = v @ Wvp{1,2}.T, stored [b][p][80] (pads zero) ----
__global__ __launch_bounds__(256) void wv12_kernel(
    const float* __restrict__ v, const float* __restrict__ WTvp,
    float* __restrict__ Wv1, float* __restrict__ Wv2)
{
    int tid = threadIdx.x;
    int p = blockIdx.x >> 3, b = blockIdx.x & 7;
    __shared__ float vrow[256];
    vrow[tid] = v[blockIdx.x * 256 + tid];   // blockIdx = p*8+b, matches v[p][b][:]
    __syncthreads();
    int ob = (b * TP + p) * THP;
    if (tid < 150) {
        float a0 = 0.f, a1 = 0.f, a2 = 0.f, a3 = 0.f;
        for (int k = 0; k < 256; k += 4) {
            a0 += vrow[k]     * WTvp[(k)     * 160 + tid];
            a1 += vrow[k + 1] * WTvp[(k + 1) * 160 + tid];
            a2 += vrow[k + 2] * WTvp[(k + 2) * 160 + tid];
            a3 += vrow[k + 3] * WTvp[(k + 3) * 160 + tid];
        }
        float acc = (a0 + a1) + (a2 + a3);
        if (tid < 75) Wv1[ob + tid] = acc;
        else          Wv2[ob + tid - 75] = acc;
    } else if (tid < 155) {
        Wv1[ob + 75 + (tid - 150)] = 0.0f;   // zero pads
    } else if (tid < 160) {
        Wv2[ob + 75 + (tid - 155)] = 0.0f;
    }
}

// -------- fused scores -> softmax(i) -> context -> build g=[v,c] ------------
// grid: b in [0,8) x 128 j-tiles of 4; block 256.  K-tiled score loop keeps
// VGPR low (16 row floats live, not 80) for occupancy.
__global__ __launch_bounds__(256) void attn_kernel(
    const float* __restrict__ v,
    const float* __restrict__ Wv1, const float* __restrict__ Wv2,
    const float* __restrict__ vw, float* __restrict__ g)
{
    int tid = threadIdx.x;
    int b  = blockIdx.x >> 7;
    int j0 = (blockIdx.x & 127) * 4;
    __shared__ float wv1j[4 * THP];
    __shared__ float vws[THP];
    __shared__ float sc[4 * TP];

    if (tid < THP) vws[tid] = (tid < TH) ? vw[tid] : 0.0f;
    for (int e = tid; e < 4 * THP; e += 256) {
        int jj = e / THP, k = e - jj * THP;
        wv1j[e] = Wv1[(b * TP + j0 + jj) * THP + k];
    }
    __syncthreads();

    float Csum = 0.0f;
    {
        const float4* c4 = (const float4*)vws;
        for (int kk = 0; kk < 20; ++kk) { float4 c = c4[kk]; Csum += c.x + c.y + c.z + c.w; }
    }

    // ---- scores: sc[jj][i] = Csum - 2 * sum_h vw[h]*rcp(1+exp(2(Wv2+Wv1)))
    for (int rep = 0; rep < 2; ++rep) {
        int i = tid + rep * 256;
        const float4* row4 = (const float4*)(Wv2 + (b * TP + i) * THP);
        float acc[4] = {0.f, 0.f, 0.f, 0.f};
#pragma unroll
        for (int kt = 0; kt < 5; ++kt) {
            float4 r0 = row4[kt * 4 + 0], r1 = row4[kt * 4 + 1];
            float4 r2 = row4[kt * 4 + 2], r3 = row4[kt * 4 + 3];
            const float4* c4 = (const float4*)(vws + kt * 16);
            float4 c0 = c4[0], c1 = c4[1], c2 = c4[2], c3 = c4[3];
#pragma unroll
            for (int jj = 0; jj < 4; ++jj) {
                const float4* w1 = (const float4*)(wv1j + jj * THP + kt * 16);
                acc[jj] += rterm4(r0, w1[0], c0) + rterm4(r1, w1[1], c1)
                         + rterm4(r2, w1[2], c2) + rterm4(r3, w1[3], c3);
            }
        }
#pragma unroll
        for (int jj = 0; jj < 4; ++jj) sc[jj * TP + i] = Csum - 2.0f * acc[jj];
    }
    __syncthreads();

    // ---- softmax over i (axis 0), one wave per jj
    {
        int jj = tid >> 6, l = tid & 63;
        float m = -1e30f;
#pragma unroll
        for (int q = 0; q < 8; ++q) m = fmaxf(m, sc[jj * TP + l + q * 64]);
#pragma unroll
        for (int s = 32; s > 0; s >>= 1) m = fmaxf(m, __shfl_xor(m, s));
        float e[8];
        float sum = 0.0f;
#pragma unroll
        for (int q = 0; q < 8; ++q) { e[q] = __expf(sc[jj * TP + l + q * 64] - m); sum += e[q]; }
#pragma unroll
        for (int s = 32; s > 0; s >>= 1) sum += __shfl_xor(sum, s);
        float inv = fast_rcp(sum);
#pragma unroll
        for (int q = 0; q < 8; ++q) sc[jj * TP + l + q * 64] = e[q] * inv;
    }
    __syncthreads();

    // ---- context: c[j,b,d] = sum_i a[i]*v[i,b,d]; thread owns d = tid
    float acc[4] = {0.f, 0.f, 0.f, 0.f};
    const float* vb = v + b * TD + tid;
    for (int i4 = 0; i4 < TP / 4; ++i4) {
        float4 a0 = ((const float4*)(sc + 0 * TP))[i4];
        float4 a1 = ((const float4*)(sc + 1 * TP))[i4];
        float4 a2 = ((const float4*)(sc + 2 * TP))[i4];
        float4 a3 = ((const float4*)(sc + 3 * TP))[i4];
#pragma unroll
        for (int u = 0; u < 4; ++u) {
            float va = vb[(i4 * 4 + u) * (TB * TD)];
            acc[0] += f4c(a0, u) * va;
            acc[1] += f4c(a1, u) * va;
            acc[2] += f4c(a2, u) * va;
            acc[3] += f4c(a3, u) * va;
        }
    }
#pragma unroll
    for (int jj = 0; jj < 4; ++jj) {
        int base = ((j0 + jj) * TB + b) * 512;
        g[base + tid]       = v[((j0 + jj) * TB + b) * TD + tid];
        g[base + 256 + tid] = acc[jj];
    }
}

// -------- fused gate (sigmoid(g Wg^T)*g) + GRU input projections ------------
__global__ __launch_bounds__(512) void gatexp_kernel(
    const float* __restrict__ g, const float* __restrict__ WgT,
    const float* __restrict__ WihT, const float* __restrict__ bihC,
    float* __restrict__ xpf, float* __restrict__ xpb)
{
    __shared__ float gt[16 * 512];      // row-major original g
    __shared__ float gT[512 * 20];      // transposed, padded stride 20: gT[k*20+r]
    int tid = threadIdx.x;
    int r0 = blockIdx.x * 16;

    const float4* gsrc = (const float4*)(g + r0 * 512);
    for (int e = tid; e < 2048; e += 512) {
        float4 vv = gsrc[e];
        ((float4*)gt)[e] = vv;
        int r = e >> 7, k4 = e & 127;
        gT[(k4 * 4 + 0) * 20 + r] = vv.x;
        gT[(k4 * 4 + 1) * 20 + r] = vv.y;
        gT[(k4 * 4 + 2) * 20 + r] = vv.z;
        gT[(k4 * 4 + 3) * 20 + r] = vv.w;
    }
    __syncthreads();

    int tx = tid & 63, w = tid >> 6;
    int rg = w >> 2;                 // rows rg*8 .. rg*8+7
    int cg = w & 3;

    float acc[8][2];
#pragma unroll
    for (int r = 0; r < 8; ++r) { acc[r][0] = 0.f; acc[r][1] = 0.f; }
    int col = cg * 128 + tx * 2;
    {
        const float* wp = WgT + col;
        const float* gp = gT + rg * 8;
#pragma unroll 4
        for (int k = 0; k < 512; ++k) {
            float2 wv = *(const float2*)wp;
            float4 ga = *(const float4*)gp;
            float4 gb = *(const float4*)(gp + 4);
            acc[0][0] += ga.x * wv.x; acc[0][1] += ga.x * wv.y;
            acc[1][0] += ga.y * wv.x; acc[1][1] += ga.y * wv.y;
            acc[2][0] += ga.z * wv.x; acc[2][1] += ga.z * wv.y;
            acc[3][0] += ga.w * wv.x; acc[3][1] += ga.w * wv.y;
            acc[4][0] += gb.x * wv.x; acc[4][1] += gb.x * wv.y;
            acc[5][0] += gb.y * wv.x; acc[5][1] += gb.y * wv.y;
            acc[6][0] += gb.z * wv.x; acc[6][1] += gb.z * wv.y;
            acc[7][0] += gb.w * wv.x; acc[7][1] += gb.w * wv.y;
            wp += 512; gp += 20;
        }
    }
    float gated[8][2];
#pragma unroll
    for (int r = 0; r < 8; ++r) {
        float2 go = *(const float2*)(gt + (rg * 8 + r) * 512 + col);
        gated[r][0] = fast_sigmoid(acc[r][0]) * go.x;
        gated[r][1] = fast_sigmoid(acc[r][1]) * go.y;
    }
    __syncthreads();
#pragma unroll
    for (int c = 0; c < 2; ++c) {
        float4 p0 = { gated[0][c], gated[1][c], gated[2][c], gated[3][c] };
        float4 p1 = { gated[4][c], gated[5][c], gated[6][c], gated[7][c] };
        *(float4*)(gT + (col + c) * 20 + rg * 8)     = p0;
        *(float4*)(gT + (col + c) * 20 + rg * 8 + 4) = p1;
    }
    __syncthreads();

    float a2[8][3];
#pragma unroll
    for (int r = 0; r < 8; ++r) { a2[r][0] = 0.f; a2[r][1] = 0.f; a2[r][2] = 0.f; }
    int col2 = cg * 192 + tx;
    {
        const float* wp = WihT + col2;
        const float* gp = gT + rg * 8;
#pragma unroll 4
        for (int k = 0; k < 512; ++k) {
            float w0 = wp[0], w1 = wp[64], w2 = wp[128];
            float4 ga = *(const float4*)gp;
            float4 gb = *(const float4*)(gp + 4);
            a2[0][0] += ga.x * w0; a2[0][1] += ga.x * w1; a2[0][2] += ga.x * w2;
            a2[1][0] += ga.y * w0; a2[1][1] += ga.y * w1; a2[1][2] += ga.y * w2;
            a2[2][0] += ga.z * w0; a2[2][1] += ga.z * w1; a2[2][2] += ga.z * w2;
            a2[3][0] += ga.w * w0; a2[3][1] += ga.w * w1; a2[3][2] += ga.w * w2;
            a2[4][0] += gb.x * w0; a2[4][1] += gb.x * w1; a2[4][2] += gb.x * w2;
            a2[5][0] += gb.y * w0; a2[5][1] += gb.y * w1; a2[5][2] += gb.y * w2;
            a2[6][0] += gb.z * w0; a2[6][1] += gb.z * w1; a2[6][2] += gb.z * w2;
            a2[7][0] += gb.w * w0; a2[7][1] += gb.w * w1; a2[7][2] += gb.w * w2;
            wp += 768; gp += 20;
        }
    }
#pragma unroll
    for (int c = 0; c < 3; ++c) {
        int oc = col2 + c * 64;
        float bv = bihC[oc];
        float* dst;
        if (oc < 384) dst = xpf + oc;
        else          dst = xpb + oc - 384;
#pragma unroll
        for (int r = 0; r < 8; ++r) {
            int row = r0 + rg * 8 + r;
            dst[row * 384] = a2[r][c] + bv;
        }
    }
}

// ---------------- GRU recurrence, one block per (dir, batch) ----------------
// 512 threads: (o = tid>>2, q = tid&3). w_hh in f16 (48 VGPRs as half2 pairs);
// h ping-pong in LDS as f16 (4 ds_read_b128/thread/step); v_dot2_f32_f16
// halves FMA issue. fp32 h kept in register for the z*h term (exact).
__global__ __launch_bounds__(512) void gru_kernel(
    const float* __restrict__ xpf, const float* __restrict__ xpb,
    const half_t* __restrict__ whh16,
    const float* __restrict__ bhhf, const float* __restrict__ bhhb,
    float* __restrict__ out)
{
    int tid = threadIdx.x;
    int dir = blockIdx.x >> 3;
    int b   = blockIdx.x & 7;
    const float* xp  = dir ? xpb  : xpf;
    const float* bhh = dir ? bhhb : bhhf;
    const half_t* wbase = whh16 + dir * 3 * TO * TO;

    __shared__ __align__(16) half_t hb[2][TO];

    int o = tid >> 2, q = tid & 3;

    H8 wr[4], wz[4], wn[4];
    {
        const half8v* pr = (const half8v*)(wbase + (0 * TO + o) * TO + q * 32);
        const half8v* pz = (const half8v*)(wbase + (1 * TO + o) * TO + q * 32 + TO * TO - TO * TO);
        pz = (const half8v*)(wbase + (TO + o) * TO + q * 32);
        const half8v* pn = (const half8v*)(wbase + (2 * TO + o) * TO + q * 32);
#pragma unroll
        for (int kk = 0; kk < 4; ++kk) { wr[kk].v8 = pr[kk]; wz[kk].v8 = pz[kk]; wn[kk].v8 = pn[kk]; }
    }

    float br = 0.f, bz = 0.f, bn = 0.f, h = 0.f;
    float xr = 0.f, xz = 0.f, xn = 0.f;
    if (q == 0) {
        br = bhh[o]; bz = bhh[TO + o]; bn = bhh[2 * TO + o];
        int t0 = dir ? (TP - 1) : 0;
        const float* xpt = xp + (t0 * TB + b) * 384;
        xr = xpt[o]; xz = xpt[TO + o]; xn = xpt[2 * TO + o];
    }
    if (tid < TO) hb[0][tid] = (half_t)0.0f;
    __syncthreads();

    for (int s = 0; s < TP; ++s) {
        int t = dir ? (TP - 1 - s) : s;
        int cur = s & 1;
        const half8v* h8 = (const half8v*)(&hb[cur][q * 32]);
        H8 hv[4];
#pragma unroll
        for (int kk = 0; kk < 4; ++kk) hv[kk].v8 = h8[kk];

        float ar = 0.f, az = 0.f, an = 0.f;
#pragma unroll
        for (int kk = 0; kk < 4; ++kk) {
#pragma unroll
            for (int j = 0; j < 4; ++j) {
                half2v hp = hv[kk].v2[j];
                ar = fdot2h(wr[kk].v2[j], hp, ar);
                az = fdot2h(wz[kk].v2[j], hp, az);
                an = fdot2h(wn[kk].v2[j], hp, an);
            }
        }
        ar += __shfl_xor(ar, 1); ar += __shfl_xor(ar, 2);
        az += __shfl_xor(az, 1); az += __shfl_xor(az, 2);
        an += __shfl_xor(an, 1); an += __shfl_xor(an, 2);
        if (q == 0) {
            float r = fast_sigmoid(xr + ar + br);
            float z = fast_sigmoid(xz + az + bz);
            float n = fast_tanh(xn + r * (an + bn));
            h = (1.0f - z) * n + z * h;
            hb[cur ^ 1][o] = (half_t)h;
            out[(t * TB + b) * 256 + dir * TO + o] = h;
            int sn = (s + 1 < TP) ? s + 1 : s;
            int tn = dir ? (TP - 1 - sn) : sn;
            const float* xpt = xp + (tn * TB + b) * 384;
            xr = xpt[o]; xz = xpt[TO + o]; xn = xpt[2 * TO + o];
        }
        __syncthreads();
    }
}

extern "C" void kernel_launch(void* const* d_in, const int* in_sizes, int n_in,
                              void* d_out, int out_size, void* d_ws, size_t ws_size,
                              hipStream_t stream) {
    const float* v    = (const float*)d_in[0];
    const float* Wvp1 = (const float*)d_in[1];
    const float* Wvp2 = (const float*)d_in[2];
    const float* vw   = (const float*)d_in[3];
    const float* Wg   = (const float*)d_in[4];
    const float* wihf = (const float*)d_in[5];
    const float* whhf = (const float*)d_in[6];
    const float* bihf = (const float*)d_in[7];
    const float* bhhf = (const float*)d_in[8];
    const float* wihb = (const float*)d_in[9];
    const float* whhb = (const float*)d_in[10];
    const float* bihb = (const float*)d_in[11];
    const float* bhhb = (const float*)d_in[12];

    float* ws   = (float*)d_ws;
    float* WTvp = ws;                    // 256*160      = 40960
    float* WgT  = WTvp + 40960;          // 512*512      = 262144
    float* WihT = WgT + 262144;          // 512*768      = 393216
    float* bihC = WihT + 393216;         // 768
    float* Wv1  = bihC + 768;            // 8*512*80     = 327680
    float* Wv2  = Wv1 + 327680;          // 327680
    float* g    = Wv2 + 327680;          // 4096*512     = 2097152
    float* xpf  = g + 2097152;           // 4096*384     = 1572864
    float* xpb  = xpf + 1572864;         // 1572864
    half_t* whh16 = (half_t*)(xpb + 1572864);  // 2*3*128*128 halves = 49152 floats
    float* out  = (float*)d_out;

    // prep total idx: 40960+262144+393216+768+98304 = 795392 = 3107*256
    prep_kernel<<<3107, 256, 0, stream>>>(Wvp1, Wvp2, Wg, wihf, wihb, bihf, bihb,
                                          whhf, whhb, WTvp, WgT, WihT, bihC, whh16);
    wv12_kernel<<<4096, 256, 0, stream>>>(v, WTvp, Wv1, Wv2);
    attn_kernel<<<1024, 256, 0, stream>>>(v, Wv1, Wv2, vw, g);
    gatexp_kernel<<<256, 512, 0, stream>>>(g, WgT, WihT, bihC, xpf, xpb);
    gru_kernel<<<16, 512, 0, stream>>>(xpf, xpb, whh16, bhhf, bhhb, out);
}